// Round 7
// baseline (175.248 us; speedup 1.0000x reference)
//
#include <hip/hip_runtime.h>
#include <hip/hip_bf16.h>
#include <stdint.h>

#define NTOK 8192
#define CD 768
#define HD 3072
#define NE 4
#define NRT 68             // 128-row tiles: sum_e ceil(n_e/128) <= 64+4
#define GCAP (NRT * 128)   // 8704 grouped (padded) rows
#define CVB 512            // wproj-cvt blocks prepended to gemm1 grid

typedef __attribute__((ext_vector_type(8))) __bf16 bf16x8;
typedef __attribute__((ext_vector_type(4))) float f32x4;

__device__ __forceinline__ void gl_lds16(const void* g, void* l) {
    __builtin_amdgcn_global_load_lds(
        (const __attribute__((address_space(1))) uint32_t*)g,
        (__attribute__((address_space(3))) uint32_t*)l, 16, 0, 0);
}

__device__ __forceinline__ unsigned bf16bits(float v) {
    __hip_bfloat16 h = __float2bfloat16(v);
    return (unsigned)*reinterpret_cast<unsigned short*>(&h);
}

__device__ __forceinline__ void cvt8(const float* __restrict__ in, __hip_bfloat16* __restrict__ out, int i) {
    float4 a = *(const float4*)(in + i);
    float4 b = *(const float4*)(in + i + 4);
    union { __hip_bfloat16 h[8]; uint4 u; } pk;
    pk.h[0] = __float2bfloat16(a.x); pk.h[1] = __float2bfloat16(a.y);
    pk.h[2] = __float2bfloat16(a.z); pk.h[3] = __float2bfloat16(a.w);
    pk.h[4] = __float2bfloat16(b.x); pk.h[5] = __float2bfloat16(b.y);
    pk.h[6] = __float2bfloat16(b.z); pk.h[7] = __float2bfloat16(b.w);
    *(uint4*)(out + i) = pk.u;
}

// -------- fused front: blocks 0..255 = router(+x cvt); blocks 256+ = wfc cvt --------
__global__ __launch_bounds__(256) void k_front(
        const float* __restrict__ x, const float* __restrict__ wr,
        const float* __restrict__ wfc,
        __hip_bfloat16* __restrict__ xb, __hip_bfloat16* __restrict__ wfcb,
        int* __restrict__ eidx, float* __restrict__ pred) {
    if (blockIdx.x >= 256) {
        const int NW = NE * HD * CD;
        const int stride = (gridDim.x - 256) * 256 * 8;
        int i0 = ((blockIdx.x - 256) * 256 + threadIdx.x) * 8;
        for (int i = i0; i < NW; i += stride) cvt8(wfc, wfcb, i);
        return;
    }
    int lane = threadIdx.x & 63;
    int wave = threadIdx.x >> 6;
    float4 wv[NE][3];
    #pragma unroll
    for (int e = 0; e < NE; ++e)
        #pragma unroll
        for (int j = 0; j < 3; ++j)
            wv[e][j] = *(const float4*)(wr + e * CD + j * 256 + lane * 4);
    float sp0 = 0.f, sp1 = 0.f, sp2 = 0.f, sp3 = 0.f, zs = 0.f, hs = 0.f;
    int c0 = 0, c1 = 0, c2 = 0, c3 = 0;
    int t0 = blockIdx.x * 32 + wave * 8;
    for (int it = 0; it < 8; ++it) {
        int t = t0 + it;
        const float* xr = x + (size_t)t * CD;
        float a0 = 0.f, a1 = 0.f, a2 = 0.f, a3 = 0.f;
        #pragma unroll
        for (int j = 0; j < 3; ++j) {
            float4 xv = *(const float4*)(xr + j * 256 + lane * 4);
            a0 += xv.x * wv[0][j].x + xv.y * wv[0][j].y + xv.z * wv[0][j].z + xv.w * wv[0][j].w;
            a1 += xv.x * wv[1][j].x + xv.y * wv[1][j].y + xv.z * wv[1][j].z + xv.w * wv[1][j].w;
            a2 += xv.x * wv[2][j].x + xv.y * wv[2][j].y + xv.z * wv[2][j].z + xv.w * wv[2][j].w;
            a3 += xv.x * wv[3][j].x + xv.y * wv[3][j].y + xv.z * wv[3][j].z + xv.w * wv[3][j].w;
        }
        #pragma unroll
        for (int off = 32; off; off >>= 1) {
            a0 += __shfl_xor(a0, off); a1 += __shfl_xor(a1, off);
            a2 += __shfl_xor(a2, off); a3 += __shfl_xor(a3, off);
        }
        if (lane == 0) {
            float l[NE] = {a0, a1, a2, a3};
            int best = 0; float m = l[0];
            #pragma unroll
            for (int e = 1; e < NE; ++e) if (l[e] > m) { m = l[e]; best = e; }
            float p[NE], s = 0.f;
            #pragma unroll
            for (int e = 0; e < NE; ++e) { p[e] = expf(l[e] - m); s += p[e]; }
            float inv = 1.f / s, ent = 0.f;
            #pragma unroll
            for (int e = 0; e < NE; ++e) {
                p[e] *= inv;
                ent -= p[e] * logf(p[e] + 1e-9f);
            }
            sp0 += p[0]; sp1 += p[1]; sp2 += p[2]; sp3 += p[3];
            float lse = m + logf(s);
            zs += lse * lse; hs += ent;
            if (best == 0) c0++; else if (best == 1) c1++; else if (best == 2) c2++; else c3++;
            eidx[t] = best;
        }
    }
    __shared__ float red[4][10];
    if (lane == 0) {
        red[wave][0] = sp0; red[wave][1] = sp1; red[wave][2] = sp2; red[wave][3] = sp3;
        red[wave][4] = zs;  red[wave][5] = hs;
        red[wave][6] = (float)c0; red[wave][7] = (float)c1;
        red[wave][8] = (float)c2; red[wave][9] = (float)c3;
    }
    __syncthreads();
    if (threadIdx.x < 10)
        pred[blockIdx.x * 10 + threadIdx.x] =
            red[0][threadIdx.x] + red[1][threadIdx.x] + red[2][threadIdx.x] + red[3][threadIdx.x];
    const float* xsrc = x + (size_t)blockIdx.x * 32 * CD;
    __hip_bfloat16* xdst = xb + (size_t)blockIdx.x * 32 * CD;
    #pragma unroll
    for (int c = 0; c < 12; ++c) cvt8(xsrc, xdst, (c * 256 + threadIdx.x) * 8);
}

// -------- reduce partials, build tile map, scalar outputs, init tlist --------
__global__ __launch_bounds__(256) void k_scan(
        const float* __restrict__ pred, int* counts, int* fill, int* tilee,
        int* tlist, float* out) {
    __shared__ float sm[10];
    if (threadIdx.x < 10) {
        float s = 0.f;
        for (int i = 0; i < 256; ++i) s += pred[i * 10 + threadIdx.x];
        sm[threadIdx.x] = s;
    }
    for (int i = threadIdx.x; i < GCAP; i += 256) tlist[i] = -1;
    __syncthreads();
    if (threadIdx.x == 0) {
        int cnt[NE];
        #pragma unroll
        for (int e = 0; e < NE; ++e) cnt[e] = (int)(sm[6 + e] + 0.5f);
        int base = 0, nt = 0;
        for (int e = 0; e < NE; ++e) {
            counts[e] = cnt[e];
            fill[e] = base;
            int tiles = (cnt[e] + 127) >> 7;
            for (int i = 0; i < tiles; ++i) tilee[nt++] = e;
            base += tiles << 7;
        }
        for (int i = nt; i < NRT; ++i) tilee[i] = -1;
        float aux = 0.f;
        for (int e = 0; e < NE; ++e)
            aux += (cnt[e] / (float)NTOK) * (sm[e] / (float)NTOK);
        out[0] = NE * aux;
        out[1] = sm[4] / (float)NTOK;
        out[2] = (sm[5] / (float)NTOK) / logf((float)NE);
        for (int e = 0; e < NE; ++e) out[3 + e] = cnt[e] / (float)NTOK;
    }
}

// wave-aggregated scatter
__global__ __launch_bounds__(256) void k_scatter(const int* __restrict__ eidx,
                                                 int* __restrict__ fill,
                                                 int* __restrict__ tlist) {
    int t = blockIdx.x * 256 + threadIdx.x;
    int e = eidx[t];
    int lane = threadIdx.x & 63;
    unsigned long long below = (1ull << lane) - 1ull;
    int base = 0;
    #pragma unroll
    for (int ee = 0; ee < NE; ++ee) {
        unsigned long long mm = __ballot(e == ee);
        if (e == ee) {
            int leader = __ffsll((unsigned long long)mm) - 1;
            int cnt = __popcll(mm);
            int b = 0;
            if (lane == leader) b = atomicAdd(&fill[ee], cnt);
            b = __shfl(b, leader);
            base = b + __popcll(mm & below);
        }
    }
    tlist[base] = t;
}

// -------- grouped GEMM: 128(M)x256(N) tile, BK=64, 4 waves (2Mx2N), 64x128/wave,
// single-buffered 48KB LDS, both-sides XOR swizzle, m97-style 2-barrier loop.
// MODE 1: hbuf = relu(Xg @ Wfc^T)^2 (bf16); first CVB blocks convert wpr -> bf16.
// MODE 2: y = Hg @ Wproj^T (f32 scatter)
template<int MODE>
__global__ __launch_bounds__(256, 2) void k_gemm(
        const __hip_bfloat16* __restrict__ A, const __hip_bfloat16* __restrict__ Bw,
        const int* __restrict__ tilee, const int* __restrict__ tlist,
        void* __restrict__ outp,
        const float* __restrict__ cvsrc, __hip_bfloat16* __restrict__ cvdst) {
    constexpr int KDIM  = (MODE == 1) ? CD : HD;
    constexpr int NBROW = (MODE == 1) ? HD : CD;
    constexpr int NCT = NBROW / 256;
    constexpr int NKT = KDIM / 64;
    constexpr int NWG = NRT * NCT;        // 816 / 204
    constexpr int Q = NWG / 8, REM = NWG % 8;

    int bid = (int)blockIdx.x;
    if constexpr (MODE == 1) {
        if (bid < CVB) {                  // prepended wproj-cvt blocks (overlap GEMM ramp)
            const int NW = NE * HD * CD;
            const int stride = CVB * 256 * 8;
            int i0 = (bid * 256 + threadIdx.x) * 8;
            for (int i = i0; i < NW; i += stride) cvt8(cvsrc, cvdst, i);
            return;
        }
        bid -= CVB;
    }
    // bijective XCD-chunked swizzle (handles NWG % 8 != 0)
    {
        int xcd = bid & 7, idx = bid >> 3;
        bid = (xcd < REM ? xcd * (Q + 1) : REM * (Q + 1) + (xcd - REM) * Q) + idx;
    }
    int rt = bid / NCT, ct = bid % NCT;   // ct-fastest: A-tile reuse within XCD
    const int e = tilee[rt];
    if (e < 0) return;

    __shared__ __align__(16) char lds[49152];   // A 16KB @0, B 32KB @16384
    const int tid = threadIdx.x;
    const int srow = tid >> 3;                   // 0..31
    const int sch = (tid & 7) ^ (srow & 7);      // pre-swizzled source chunk (rule #21)

    const __hip_bfloat16* ap[4];
    #pragma unroll
    for (int i = 0; i < 4; ++i) {
        int r = i * 32 + srow;
        if constexpr (MODE == 1) {
            int gt = tlist[rt * 128 + r];
            if (gt < 0) gt = 0;
            ap[i] = A + (size_t)gt * KDIM + sch * 8;
        } else {
            ap[i] = A + ((size_t)rt * 128 + r) * KDIM + sch * 8;
        }
    }
    const __hip_bfloat16* bp = Bw + ((size_t)e * NBROW + ct * 256 + srow) * KDIM + sch * 8;

    const int wv = tid >> 6, lane = tid & 63;
    const int wm = wv >> 1, wn = wv & 1;         // 2M x 2N, per-wave 64x128
    const int lr = lane & 15, lq = lane >> 4;

    f32x4 acc[4][8];
    #pragma unroll
    for (int m = 0; m < 4; ++m)
        #pragma unroll
        for (int n = 0; n < 8; ++n) acc[m][n] = (f32x4){0.f, 0.f, 0.f, 0.f};

    #pragma unroll 1
    for (int kt = 0; kt < NKT; ++kt) {
        __syncthreads();
        #pragma unroll
        for (int i = 0; i < 4; ++i)
            gl_lds16(ap[i] + kt * 64, lds + (i * 256 + tid) * 16);
        #pragma unroll
        for (int i = 0; i < 8; ++i)
            gl_lds16(bp + (size_t)i * 32 * KDIM + kt * 64, lds + 16384 + (i * 256 + tid) * 16);
        __syncthreads();
        #pragma unroll
        for (int kh = 0; kh < 2; ++kh) {
            bf16x8 afr[4], bfr[8];
            #pragma unroll
            for (int m = 0; m < 4; ++m) {
                int r = wm * 64 + m * 16 + lr;
                afr[m] = *(const bf16x8*)(lds + r * 128 + (((kh * 4 + lq) ^ (r & 7)) << 4));
            }
            #pragma unroll
            for (int n = 0; n < 8; ++n) {
                int r = wn * 128 + n * 16 + lr;
                bfr[n] = *(const bf16x8*)(lds + 16384 + r * 128 + (((kh * 4 + lq) ^ (r & 7)) << 4));
            }
            __builtin_amdgcn_s_setprio(1);
            #pragma unroll
            for (int m = 0; m < 4; ++m)
                #pragma unroll
                for (int n = 0; n < 8; ++n)
                    acc[m][n] = __builtin_amdgcn_mfma_f32_16x16x32_bf16(afr[m], bfr[n], acc[m][n], 0, 0, 0);
            __builtin_amdgcn_s_setprio(0);
        }
    }

    if constexpr (MODE == 1) {
        __hip_bfloat16* hbuf = (__hip_bfloat16*)outp;
        int colb = ct * 256 + wn * 128;
        #pragma unroll
        for (int m = 0; m < 4; ++m) {
            int row0 = rt * 128 + wm * 64 + m * 16 + lq * 4;
            #pragma unroll
            for (int n = 0; n < 8; ++n) {
                #pragma unroll
                for (int q = 0; q < 4; ++q) {
                    float v = fmaxf(acc[m][n][q], 0.f);
                    v *= v;
                    unsigned b = bf16bits(v);
                    unsigned ob = (unsigned)__shfl_xor((int)b, 1);
                    if (!(lane & 1))
                        *(unsigned*)(hbuf + (size_t)(row0 + q) * HD + colb + n * 16 + (lr & 14)) = b | (ob << 16);
                }
            }
        }
    } else {
        float* y = (float*)outp;
        #pragma unroll
        for (int m = 0; m < 4; ++m) {
            #pragma unroll
            for (int q = 0; q < 4; ++q) {
                int grow = rt * 128 + wm * 64 + m * 16 + lq * 4 + q;
                int t = tlist[grow];
                if (t >= 0) {
                    float* yp = y + (size_t)t * CD + ct * 256 + wn * 128 + lr;
                    #pragma unroll
                    for (int n = 0; n < 8; ++n) yp[n * 16] = acc[m][n][q];
                }
            }
        }
    }
}

extern "C" void kernel_launch(void* const* d_in, const int* in_sizes, int n_in,
                              void* d_out, int out_size, void* d_ws, size_t ws_size,
                              hipStream_t stream) {
    const float* x   = (const float*)d_in[0];
    const float* wr  = (const float*)d_in[1];
    const float* wfc = (const float*)d_in[2];
    const float* wpr = (const float*)d_in[3];
    float* y = (float*)d_out;

    char* ws = (char*)d_ws;
    int*   eidx   = (int*)ws;                          // 8192 ints
    int*   counts = (int*)(ws + 32768);
    int*   fill   = (int*)(ws + 32800);
    int*   tilee  = (int*)(ws + 32832);                // 68 ints
    float* pred   = (float*)(ws + 33152);              // 256*10 floats
    int*   tlist  = (int*)(ws + 43520);                // 8704 ints
    __hip_bfloat16* xb   = (__hip_bfloat16*)(ws + 78848);                 // 12.6 MB
    __hip_bfloat16* wfcb = (__hip_bfloat16*)(ws + 78848 + 12582912);      // 18.9 MB
    __hip_bfloat16* wprb = (__hip_bfloat16*)(ws + 78848 + 12582912 + 18874368);
    __hip_bfloat16* hbuf = (__hip_bfloat16*)(ws + 78848 + 12582912 + 2 * 18874368);
    // total ws use ~104 MB

    k_front<<<256 + 1024, 256, 0, stream>>>(x, wr, wfc, xb, wfcb, eidx, pred);
    k_scan<<<1, 256, 0, stream>>>(pred, counts, fill, tilee, tlist,
                                  y + (size_t)NTOK * CD);
    k_scatter<<<NTOK / 256, 256, 0, stream>>>(eidx, fill, tlist);
    k_gemm<1><<<CVB + NRT * (HD / 256), 256, 0, stream>>>(xb, wfcb, tilee, tlist, hbuf,
                                                          wpr, wprb);
    k_gemm<2><<<NRT * (CD / 256), 256, 0, stream>>>(hbuf, wprb, tilee, tlist, y,
                                                    nullptr, nullptr);
}